// Round 7
// baseline (510.596 us; speedup 1.0000x reference)
//
#include <hip/hip_runtime.h>
#include <math.h>

// Problem constants (fixed by reference setup_inputs)
#define S     2048
#define DK    64
#define NBH   32
#define NBLK  1024
#define KP_OFF 4096          // byte offset of packed K inside ws

typedef __bf16 bf16x8 __attribute__((ext_vector_type(8)));
typedef float  f32x4  __attribute__((ext_vector_type(4)));

enum { M_CTRL = 0, M_NOLOAD = 1, M_NOEXP = 2, M_DEEP8 = 3, M_FB = 4 };

__device__ __forceinline__ unsigned pk_bf16(float lo, float hi) {
    return __builtin_amdgcn_perm(__builtin_bit_cast(unsigned, hi),
                                 __builtin_bit_cast(unsigned, lo),
                                 0x07060302u);
}
__device__ __forceinline__ float gelu_exact(float x) {
    return 0.5f * x * (1.0f + erff(x * 0.70710678118654752f));
}

// ---------------------------------------------------------------------------
// Pre-pass: K fp32 -> bf16 packed B-fragment-major (same as R6):
//   Kp[bh][frag u(16 rows)][half][lane][8]
// ---------------------------------------------------------------------------
__global__ __launch_bounds__(256) void convert_pack_k(
    const float* __restrict__ K, unsigned short* __restrict__ Kp)
{
    const unsigned tau = blockIdx.x * 256 + threadIdx.x;
    const int lane = tau & 63;
    const int half = (tau >> 6) & 1;
    const int u    = (tau >> 7) & 127;
    const int bh   = tau >> 14;
    const float* src = K + (size_t)(bh * S + u * 16 + (lane & 15)) * DK
                         + half * 32 + (lane >> 4) * 8;
    const float4 a = *(const float4*)src;
    const float4 b = *(const float4*)(src + 4);
    uint4 o;
    o.x = pk_bf16(a.x, a.y); o.y = pk_bf16(a.z, a.w);
    o.z = pk_bf16(b.x, b.y); o.w = pk_bf16(b.z, b.w);
    *(uint4*)(Kp + (size_t)tau * 8) = o;
}

// ---------------------------------------------------------------------------
// ABLATION TEMPLATE. All modes share: XCD work-queue, A-fragment build,
// 64-iteration main loop shape, per-mode ablated component (see top comment).
// M_CTRL is byte-for-byte the R6 structure and alone produces output/stats.
// Probes sink their results into ws[256..319] (never read).
// ---------------------------------------------------------------------------
template<int MODE>
__global__ __launch_bounds__(256, 4) void attn_probe(
    const float* __restrict__ Q, const float* __restrict__ K,
    const unsigned short* __restrict__ Kp,
    const float* __restrict__ W1, const float* __restrict__ b1,
    const float* __restrict__ W2, const float* __restrict__ b2,
    const float* __restrict__ W3, const float* __restrict__ b3,
    float* __restrict__ ws, float* __restrict__ out)
{
    __shared__ float mM[2][64], zM[2][64], z2M[2][64];
    __shared__ float smW[4];
    __shared__ int   workS[2];
    __shared__ int   lastF;
    __shared__ float H1[32 * 65];
    __shared__ float featL[128];

    const int t    = threadIdx.x;
    const int lane = t & 63;
    const int w    = t >> 6;
    const int qg   = w & 1;
    const int kg   = w >> 1;
    const int lrow = lane & 15;
    const int lq   = lane >> 4;

    // ---- XCD-local work queue (own counter slice per mode) ----
    if (t == 0) {
        unsigned xcc;
        asm volatile("s_getreg_b32 %0, hwreg(20, 0, 4)" : "=s"(xcc));
        const int slice = (MODE == M_FB) ? 0 : MODE;
        int* qcnt = (int*)ws + 100 + slice * 8;
        int item = 0;
        for (int a = 0; a < 8; ++a) {
            const int qx = (xcc + a) & 7;
            const int old = atomicAdd(&qcnt[qx], 1);
            if (old < 128) { item = qx * 128 + old; break; }
        }
        workS[0] = (item >> 7) * 4 + (item & 3);
        workS[1] = (item & 127) >> 2;
    }
    __syncthreads();
    const int bh = workS[0];
    const int qt = workS[1];

    const float* Qb = Q + (size_t)(bh * S + qt * 64) * DK;
    const float QSC = 0.18033688011112042f;   // 0.125 * log2(e)
    bf16x8 aLo[2], aHi[2];
#pragma unroll
    for (int g = 0; g < 2; ++g) {
        const float* qp = Qb + (qg * 32 + g * 16 + lrow) * DK + lq * 8;
        const float4 v0 = *(const float4*)qp;
        const float4 v1 = *(const float4*)(qp + 4);
        const float4 v2 = *(const float4*)(qp + 32);
        const float4 v3 = *(const float4*)(qp + 36);
        uint4 lo, hi;
        lo.x = pk_bf16(v0.x * QSC, v0.y * QSC);
        lo.y = pk_bf16(v0.z * QSC, v0.w * QSC);
        lo.z = pk_bf16(v1.x * QSC, v1.y * QSC);
        lo.w = pk_bf16(v1.z * QSC, v1.w * QSC);
        hi.x = pk_bf16(v2.x * QSC, v2.y * QSC);
        hi.y = pk_bf16(v2.z * QSC, v2.w * QSC);
        hi.z = pk_bf16(v3.x * QSC, v3.y * QSC);
        hi.w = pk_bf16(v3.z * QSC, v3.w * QSC);
        aLo[g] = __builtin_bit_cast(bf16x8, lo);
        aHi[g] = __builtin_bit_cast(bf16x8, hi);
    }

    float m[8], Zs[8], Z2[8], sml = 0.0f;
#pragma unroll
    for (int j = 0; j < 8; ++j) { m[j] = -INFINITY; Zs[j] = 0.f; Z2[j] = 0.f; }

    // full stats update (CTRL / NOLOAD / DEEP8 / FB)
    auto upd = [&](const f32x4& a0, const f32x4& a1) {
#pragma unroll
        for (int i = 0; i < 4; ++i) {
            const float s0 = a0[i];
            const float p0 = __builtin_amdgcn_exp2f(s0);
            m[i]  = fmaxf(m[i], s0);
            Zs[i] += p0;
            Z2[i] = fmaf(p0, p0, Z2[i]);
            sml += s0;
            const float s1 = a1[i];
            const float p1 = __builtin_amdgcn_exp2f(s1);
            m[4 + i]  = fmaxf(m[4 + i], s1);
            Zs[4 + i] += p1;
            Z2[4 + i] = fmaf(p1, p1, Z2[4 + i]);
            sml += s1;
        }
    };

    const unsigned short* pw = Kp + (size_t)(bh * 128 + kg * 64) * 1024 + lane * 8;

    if (MODE == M_CTRL || MODE == M_NOEXP) {
        uint4 rl[4], rh[4];
#pragma unroll
        for (int j = 0; j < 4; ++j) {
            rl[j] = *(const uint4*)(pw + j * 1024);
            rh[j] = *(const uint4*)(pw + j * 1024 + 512);
        }
#pragma unroll 4
        for (int u = 0; u < 64; ++u) {
            const int j = u & 3;
            const bf16x8 bLo = __builtin_bit_cast(bf16x8, rl[j]);
            const bf16x8 bHi = __builtin_bit_cast(bf16x8, rh[j]);
            if (u + 4 < 64) {
                rl[j] = *(const uint4*)(pw + (size_t)(u + 4) * 1024);
                rh[j] = *(const uint4*)(pw + (size_t)(u + 4) * 1024 + 512);
            }
            f32x4 acc0 = {0.f, 0.f, 0.f, 0.f}, acc1 = {0.f, 0.f, 0.f, 0.f};
            acc0 = __builtin_amdgcn_mfma_f32_16x16x32_bf16(aLo[0], bLo, acc0, 0, 0, 0);
            acc0 = __builtin_amdgcn_mfma_f32_16x16x32_bf16(aHi[0], bHi, acc0, 0, 0, 0);
            acc1 = __builtin_amdgcn_mfma_f32_16x16x32_bf16(aLo[1], bLo, acc1, 0, 0, 0);
            acc1 = __builtin_amdgcn_mfma_f32_16x16x32_bf16(aHi[1], bHi, acc1, 0, 0, 0);
            if (MODE == M_NOEXP) {
#pragma unroll
                for (int i = 0; i < 4; ++i) sml += acc0[i] + acc1[i];
            } else {
                upd(acc0, acc1);
            }
        }
    } else if (MODE == M_DEEP8) {
        uint4 rl[8], rh[8];
#pragma unroll
        for (int j = 0; j < 8; ++j) {
            rl[j] = *(const uint4*)(pw + j * 1024);
            rh[j] = *(const uint4*)(pw + j * 1024 + 512);
        }
#pragma unroll 8
        for (int u = 0; u < 64; ++u) {
            const int j = u & 7;
            const bf16x8 bLo = __builtin_bit_cast(bf16x8, rl[j]);
            const bf16x8 bHi = __builtin_bit_cast(bf16x8, rh[j]);
            if (u + 8 < 64) {
                rl[j] = *(const uint4*)(pw + (size_t)(u + 8) * 1024);
                rh[j] = *(const uint4*)(pw + (size_t)(u + 8) * 1024 + 512);
            }
            f32x4 acc0 = {0.f, 0.f, 0.f, 0.f}, acc1 = {0.f, 0.f, 0.f, 0.f};
            acc0 = __builtin_amdgcn_mfma_f32_16x16x32_bf16(aLo[0], bLo, acc0, 0, 0, 0);
            acc0 = __builtin_amdgcn_mfma_f32_16x16x32_bf16(aHi[0], bHi, acc0, 0, 0, 0);
            acc1 = __builtin_amdgcn_mfma_f32_16x16x32_bf16(aLo[1], bLo, acc1, 0, 0, 0);
            acc1 = __builtin_amdgcn_mfma_f32_16x16x32_bf16(aHi[1], bHi, acc1, 0, 0, 0);
            upd(acc0, acc1);
        }
    } else if (MODE == M_NOLOAD) {
        uint4 rl[4], rh[4];
#pragma unroll
        for (int j = 0; j < 4; ++j) {
            rl[j] = *(const uint4*)(pw + j * 1024);
            rh[j] = *(const uint4*)(pw + j * 1024 + 512);
        }
        for (int u = 0; u < 64; ++u) {
            const int j = u & 3;
            uint4 tl = rl[j], th = rh[j];
            tl.x ^= (unsigned)u;  th.x ^= (unsigned)u;   // defeat hoisting
            const bf16x8 bLo = __builtin_bit_cast(bf16x8, tl);
            const bf16x8 bHi = __builtin_bit_cast(bf16x8, th);
            f32x4 acc0 = {0.f, 0.f, 0.f, 0.f}, acc1 = {0.f, 0.f, 0.f, 0.f};
            acc0 = __builtin_amdgcn_mfma_f32_16x16x32_bf16(aLo[0], bLo, acc0, 0, 0, 0);
            acc0 = __builtin_amdgcn_mfma_f32_16x16x32_bf16(aHi[0], bHi, acc0, 0, 0, 0);
            acc1 = __builtin_amdgcn_mfma_f32_16x16x32_bf16(aLo[1], bLo, acc1, 0, 0, 0);
            acc1 = __builtin_amdgcn_mfma_f32_16x16x32_bf16(aHi[1], bHi, acc1, 0, 0, 0);
            upd(acc0, acc1);
        }
    } else { // M_FB: fp32 scattered fallback (correct, slower)
        const float* Kw = K + (size_t)(bh * S + kg * 1024 + lrow) * DK + lq * 8;
        for (int u = 0; u < 64; ++u) {
            const float* p = Kw + (size_t)u * 16 * DK;
            const float4 v0 = *(const float4*)p;
            const float4 v1 = *(const float4*)(p + 4);
            const float4 v2 = *(const float4*)(p + 32);
            const float4 v3 = *(const float4*)(p + 36);
            uint4 lo, hi;
            lo.x = pk_bf16(v0.x, v0.y); lo.y = pk_bf16(v0.z, v0.w);
            lo.z = pk_bf16(v1.x, v1.y); lo.w = pk_bf16(v1.z, v1.w);
            hi.x = pk_bf16(v2.x, v2.y); hi.y = pk_bf16(v2.z, v2.w);
            hi.z = pk_bf16(v3.x, v3.y); hi.w = pk_bf16(v3.z, v3.w);
            const bf16x8 bLo = __builtin_bit_cast(bf16x8, lo);
            const bf16x8 bHi = __builtin_bit_cast(bf16x8, hi);
            f32x4 acc0 = {0.f, 0.f, 0.f, 0.f}, acc1 = {0.f, 0.f, 0.f, 0.f};
            acc0 = __builtin_amdgcn_mfma_f32_16x16x32_bf16(aLo[0], bLo, acc0, 0, 0, 0);
            acc0 = __builtin_amdgcn_mfma_f32_16x16x32_bf16(aHi[0], bHi, acc0, 0, 0, 0);
            acc1 = __builtin_amdgcn_mfma_f32_16x16x32_bf16(aLo[1], bLo, acc1, 0, 0, 0);
            acc1 = __builtin_amdgcn_mfma_f32_16x16x32_bf16(aHi[1], bHi, acc1, 0, 0, 0);
            upd(acc0, acc1);
        }
    }

    // ---- probes: cheap sink and exit ----
    if (MODE == M_NOLOAD || MODE == M_NOEXP || MODE == M_DEEP8) {
        float g = sml;
        if (MODE != M_NOEXP) {
#pragma unroll
            for (int j = 0; j < 8; ++j) g += m[j] + Zs[j] + Z2[j];
        }
#pragma unroll
        for (int off = 1; off < 64; off <<= 1) g += __shfl_xor(g, off, 64);
        if (lane == 0) atomicAdd(&ws[256 + (blockIdx.x & 63)], g);
        return;
    }

    // ---- CTRL/FB: full reduction, stats, finish counter, MLP ----
#pragma unroll
    for (int off = 1; off < 16; off <<= 1)
#pragma unroll
        for (int j = 0; j < 8; ++j) {
            m[j]   = fmaxf(m[j], __shfl_xor(m[j], off, 64));
            Zs[j] += __shfl_xor(Zs[j], off, 64);
            Z2[j] += __shfl_xor(Z2[j], off, 64);
        }
#pragma unroll
    for (int off = 1; off < 64; off <<= 1) sml += __shfl_xor(sml, off, 64);

    if (lane == 0) smW[w] = sml;
    if (lrow == 0) {
#pragma unroll
        for (int g = 0; g < 2; ++g)
#pragma unroll
            for (int i = 0; i < 4; ++i) {
                const int r = qg * 32 + g * 16 + lq * 4 + i;
                const int j = g * 4 + i;
                mM[kg][r] = m[j]; zM[kg][r] = Zs[j]; z2M[kg][r] = Z2[j];
            }
    }
    __syncthreads();

    if (t < 64) {
        const float LN2 = 0.6931471805599453f;
        const int r = t;
        const float mm  = fmaxf(mM[0][r], mM[1][r]);
        const float Zr  = zM[0][r] + zM[1][r];
        const float Z2r = z2M[0][r] + z2M[1][r];
        const float iz = 1.0f / Zr;
        float pvar = (Z2r * iz * iz - (1.0f / 2048.0f)) * (1.0f / 2047.0f);
        float pmax = mm * LN2;
#pragma unroll
        for (int off = 1; off < 64; off <<= 1) {
            pvar += __shfl_xor(pvar, off, 64);
            pmax += __shfl_xor(pmax, off, 64);
        }
        if (t == 0) {
            const float smT = (smW[0] + smW[1] + smW[2] + smW[3]) * LN2;
            atomicAdd(&ws[bh * 3 + 0], smT);
            atomicAdd(&ws[bh * 3 + 1], pmax);
            atomicAdd(&ws[bh * 3 + 2], pvar);
            __threadfence();
            const int old = atomicAdd((int*)ws + 96, 1);
            lastF = (old == NBLK - 1);
        }
    }
    __syncthreads();
    if (!lastF) return;

    float* logtL = featL + 96;
    if (t < 96)             featL[t] = atomicAdd(&ws[t], 0.0f);
    if (t >= 96 && t < 128) logtL[t - 96] = 0.0f;
    __syncthreads();

    if (t < 64) {
        const float w1a = W1[t], w1b = W1[64 + t], w1c = W1[128 + t], bb1 = b1[t];
        for (int b = 0; b < 32; ++b) {
            const float f0 = featL[b * 3 + 0] * (1.0f / ((float)S * (float)S));
            const float f1 = featL[b * 3 + 1] * (1.0f / (float)S);
            const float f2 = featL[b * 3 + 2] * (1.0f / (float)S);
            H1[b * 65 + t] = gelu_exact(f0 * w1a + f1 * w1b + f2 * w1c + bb1);
        }
    }
    __syncthreads();
    {
        const int b = t >> 3, jb = (t & 7) * 8;
        float acc[8];
#pragma unroll
        for (int u = 0; u < 8; ++u) acc[u] = 0.0f;
        for (int k = 0; k < 64; ++k) {
            const float hk = H1[b * 65 + k];
            const float4 wa = *(const float4*)&W2[k * 64 + jb];
            const float4 wb = *(const float4*)&W2[k * 64 + jb + 4];
            acc[0] += hk * wa.x; acc[1] += hk * wa.y;
            acc[2] += hk * wa.z; acc[3] += hk * wa.w;
            acc[4] += hk * wb.x; acc[5] += hk * wb.y;
            acc[6] += hk * wb.z; acc[7] += hk * wb.w;
        }
        float part = 0.0f;
#pragma unroll
        for (int u = 0; u < 8; ++u)
            part += gelu_exact(acc[u] + b2[jb + u]) * W3[jb + u];
        atomicAdd(&logtL[b], part);
    }
    __syncthreads();
    if (t < 32) {
        float lt = logtL[t] + b3[0];
        lt = fminf(fmaxf(lt, -2.3025850929940457f), 2.3025850929940457f);
        out[t] = expf(lt);
    }
}

// ---------------------------------------------------------------------------
extern "C" void kernel_launch(void* const* d_in, const int* in_sizes, int n_in,
                              void* d_out, int out_size, void* d_ws, size_t ws_size,
                              hipStream_t stream)
{
    const float* Q  = (const float*)d_in[0];
    const float* K  = (const float*)d_in[1];
    const float* W1 = (const float*)d_in[2];
    const float* b1 = (const float*)d_in[3];
    const float* W2 = (const float*)d_in[4];
    const float* b2 = (const float*)d_in[5];
    const float* W3 = (const float*)d_in[6];
    const float* b3 = (const float*)d_in[7];
    float* out = (float*)d_out;
    float* ws  = (float*)d_ws;
    unsigned short* Kp = (unsigned short*)((char*)d_ws + KP_OFF);

    // zero stats accumulators, finish counter, per-mode queue counters, sinks
    hipMemsetAsync(ws, 0, KP_OFF, stream);

    const size_t needed = KP_OFF + (size_t)NBH * S * DK * sizeof(unsigned short);
    if (ws_size >= needed) {
        convert_pack_k<<<2048, 256, 0, stream>>>(K, Kp);
        attn_probe<M_NOLOAD><<<NBLK, 256, 0, stream>>>(Q, K, Kp, W1, b1, W2, b2, W3, b3, ws, out);
        attn_probe<M_NOEXP ><<<NBLK, 256, 0, stream>>>(Q, K, Kp, W1, b1, W2, b2, W3, b3, ws, out);
        attn_probe<M_DEEP8 ><<<NBLK, 256, 0, stream>>>(Q, K, Kp, W1, b1, W2, b2, W3, b3, ws, out);
        attn_probe<M_CTRL  ><<<NBLK, 256, 0, stream>>>(Q, K, Kp, W1, b1, W2, b2, W3, b3, ws, out);
    } else {
        attn_probe<M_FB><<<NBLK, 256, 0, stream>>>(Q, K, Kp, W1, b1, W2, b2, W3, b3, ws, out);
    }
}